// Round 1
// baseline (478.297 us; speedup 1.0000x reference)
//
#include <hip/hip_runtime.h>
#include <math.h>

#define N_SAMP 16384
#define DIN 128
#define FDIM 128
#define BINS 32
#define NEDGE 33
#define CELLS (FDIM * NEDGE)   // 4224
#define H1 1024
#define H2 512
#define NC 10

#define NP 512                 // phase-1 partials (== grid)
#define ROWS 32                // 512*32 = 16384 samples
#define XBS 136                // bf16 x-tile stride (shorts): 272B rows
#define SSS 132                // fp32 s-tile stride (floats): 2-way banks (free)
#define GRID 512               // 2 blocks/CU x 256 CUs -> all co-resident

#define EXP_3_125 22.7598950f  // e^3.125

typedef __attribute__((ext_vector_type(8))) short bf16x8;
typedef __attribute__((ext_vector_type(4))) float f32x4;

__device__ __forceinline__ float sig_from_t(float t) {
    // sigma = 1/(1+t), t = e^{-z}; t->0 => 1, t->inf => 0 (exact saturation)
    return __builtin_amdgcn_rcpf(1.f + t);
}
__device__ __forceinline__ float lrelu(float x) { return x > 0.f ? x : 0.01f * x; }
__device__ __forceinline__ unsigned short f2bf(float f) {   // RNE fp32->bf16
    unsigned int u = __float_as_uint(f);
    u += 0x7FFF + ((u >> 16) & 1);
    return (unsigned short)(u >> 16);
}

__device__ __forceinline__ void sig_chain4(float za, float zb, float zc, float zd,
                                           float* locE) {
    // four interleaved telescoped chains (row quad) for 4x trans-unit ILP
    float ta = __expf(za), tb = __expf(zb), tc = __expf(zc), td = __expf(zd);
    #pragma unroll
    for (int j = 0; j < 12; ++j) {
        locE[j] += (sig_from_t(ta) + sig_from_t(tb)) +
                   (sig_from_t(tc) + sig_from_t(td));
        ta *= EXP_3_125; tb *= EXP_3_125; tc *= EXP_3_125; td *= EXP_3_125;
    }
}

// ---------------------------------------------------------------------------
// Grid barrier: 8 cache-line-padded monotonic counters (64 blocks each),
// device-scope atomics. Counters are zeroed by a memset node each launch
// (workspace is harness-poisoned, so no state survives). Failsafe timeout
// breaks the spin after ~20ms so a co-residency miss fails fast, not hangs.
// ---------------------------------------------------------------------------
__device__ __forceinline__ void gsync(unsigned* bar, unsigned phase) {
    __syncthreads();
    if (threadIdx.x == 0) {
        __threadfence();
        __hip_atomic_fetch_add(&bar[(blockIdx.x & 7) * 16], 1u,
                               __ATOMIC_RELEASE, __HIP_MEMORY_SCOPE_AGENT);
        const unsigned tgt = phase * (GRID / 8);
        const unsigned long long t0 = __builtin_amdgcn_s_memrealtime();
        for (;;) {
            unsigned mn = 0xffffffffu;
            #pragma unroll
            for (int i = 0; i < 8; ++i)
                mn = min(mn, __hip_atomic_load(&bar[i * 16], __ATOMIC_ACQUIRE,
                                               __HIP_MEMORY_SCOPE_AGENT));
            if (mn >= tgt) break;
            if (__builtin_amdgcn_s_memrealtime() - t0 > 2000000ull) break;
            __builtin_amdgcn_s_sleep(2);
        }
        __threadfence();
    }
    __syncthreads();
}

// ---------------------------------------------------------------------------
// Fused persistent kernel: 512 blocks x 256 threads, 5 phases, 4 grid syncs.
// Phase bodies are bit-identical to the verified 5-kernel version.
// ---------------------------------------------------------------------------
__global__ __launch_bounds__(256, 2) void fused_all(
    const float* __restrict__ x, const float* __restrict__ Wf,
    const float* __restrict__ bfeat,
    const float* __restrict__ W1, const float* __restrict__ b1,
    const float* __restrict__ W2, const float* __restrict__ b2,
    const float* __restrict__ W3, const float* __restrict__ b3,
    float* __restrict__ E_part, float* __restrict__ E16,
    float* __restrict__ h1_part, float* __restrict__ h2_part,
    float* __restrict__ out, unsigned* __restrict__ bar)
{
    __shared__ __align__(16) char smem[ROWS * XBS * 2 + ROWS * SSS * 4]; // 25600 B
    const int t = threadIdx.x;
    const int blk = blockIdx.x;

    // ======================= Phase 1: feats GEMM + sigmoid + hist ==========
    {
        unsigned short* xbf = (unsigned short*)smem;            // 8704 B
        float* s = (float*)(smem + ROWS * XBS * 2);             // 16896 B
        const int w = t >> 6, L = t & 63;
        const int m = L & 15, q = L >> 4;

        // B fragments straight from L2-hot Wf (transposed access)
        bf16x8 bfrag[2][4];
        #pragma unroll
        for (int fh = 0; fh < 2; ++fh) {
            const int n = w * 32 + fh * 16 + m;
            #pragma unroll
            for (int kc = 0; kc < 4; ++kc) {
                const float* wp = Wf + (size_t)(kc * 32 + q * 8) * FDIM + n;
                bf16x8 bfv;
                #pragma unroll
                for (int j = 0; j < 8; ++j)
                    bfv[j] = (short)f2bf(wp[j * FDIM]);
                bfrag[fh][kc] = bfv;
            }
        }

        // stage x tile as bf16: 32 rows x 128 cols
        const int row0 = blk * ROWS;
        #pragma unroll
        for (int i = 0; i < 4; ++i) {
            const int idx = t + i * 256;
            const int r = idx >> 5, c4 = (idx & 31) << 2;
            const float4 v = *(const float4*)(x + (size_t)(row0 + r) * DIN + c4);
            unsigned short* p = &xbf[r * XBS + c4];
            p[0] = f2bf(v.x); p[1] = f2bf(v.y); p[2] = f2bf(v.z); p[3] = f2bf(v.w);
        }
        __syncthreads();

        f32x4 acc[2][2];
        #pragma unroll
        for (int rt = 0; rt < 2; ++rt)
            #pragma unroll
            for (int fh = 0; fh < 2; ++fh)
                acc[rt][fh] = (f32x4){0.f, 0.f, 0.f, 0.f};

        #pragma unroll
        for (int kc = 0; kc < 4; ++kc) {
            const bf16x8 a0 = *(const bf16x8*)&xbf[m * XBS + kc * 32 + q * 8];
            const bf16x8 a1 = *(const bf16x8*)&xbf[(16 + m) * XBS + kc * 32 + q * 8];
            acc[0][0] = __builtin_amdgcn_mfma_f32_16x16x32_bf16(a0, bfrag[0][kc], acc[0][0], 0, 0, 0);
            acc[0][1] = __builtin_amdgcn_mfma_f32_16x16x32_bf16(a0, bfrag[1][kc], acc[0][1], 0, 0, 0);
            acc[1][0] = __builtin_amdgcn_mfma_f32_16x16x32_bf16(a1, bfrag[0][kc], acc[1][0], 0, 0, 0);
            acc[1][1] = __builtin_amdgcn_mfma_f32_16x16x32_bf16(a1, bfrag[1][kc], acc[1][1], 0, 0, 0);
        }

        // sigmoid epilogue in C-layout: col = m (feat), row = q*4 + reg
        {
            const int f0 = w * 32 + m;
            const float bb0 = bfeat[f0], bb1 = bfeat[f0 + 16];
            #pragma unroll
            for (int rt = 0; rt < 2; ++rt)
                #pragma unroll
                for (int r = 0; r < 4; ++r) {
                    const int row = rt * 16 + q * 4 + r;
                    s[row * SSS + f0]      = sig_from_t(__expf(-(acc[rt][0][r] + bb0)));
                    s[row * SSS + f0 + 16] = sig_from_t(__expf(-(acc[rt][1][r] + bb1)));
                }
        }
        __syncthreads();

        // trimmed edge sums: thread = (feat, half); 12 chained edges each
        const int feat = t & 127;
        const int eg = t >> 7;                       // wave-uniform
        const float c0 = eg ? 50.0f : 12.5f;

        float locE[12];
        #pragma unroll
        for (int j = 0; j < 12; ++j) locE[j] = 0.f;

        for (int r = 0; r < ROWS; r += 4) {
            const float za = c0 - 100.f * s[r * SSS + feat];
            const float zb = c0 - 100.f * s[(r + 1) * SSS + feat];
            const float zc = c0 - 100.f * s[(r + 2) * SSS + feat];
            const float zd = c0 - 100.f * s[(r + 3) * SSS + feat];
            sig_chain4(za, zb, zc, zd, locE);
        }

        float* dst = E_part + (size_t)blk * CELLS + feat;
        if (eg == 0) {
            #pragma unroll
            for (int j = 0; j < 4; ++j)  dst[j * FDIM] = (float)ROWS;
            #pragma unroll
            for (int j = 0; j < 12; ++j) dst[(4 + j) * FDIM] = locE[j];
        } else {
            #pragma unroll
            for (int j = 0; j < 12; ++j) dst[(16 + j) * FDIM] = locE[j];
            #pragma unroll
            for (int j = 28; j < 33; ++j) dst[j * FDIM] = 0.f;
        }
    }
    gsync(bar, 1);

    // ======================= Phase 2: reduce 512 -> 16 partials ============
    {
        const unsigned G = (unsigned)blk * 256u + (unsigned)t;
        if (G < 16u * CELLS) {
            const unsigned pg = G / CELLS, cell = G % CELLS;
            const float* p = E_part + (size_t)pg * 32 * CELLS + cell;
            float a0 = 0, a1 = 0, a2 = 0, a3 = 0;
            #pragma unroll
            for (int qq = 0; qq < 32; qq += 4) {
                a0 += p[(size_t)(qq + 0) * CELLS];
                a1 += p[(size_t)(qq + 1) * CELLS];
                a2 += p[(size_t)(qq + 2) * CELLS];
                a3 += p[(size_t)(qq + 3) * CELLS];
            }
            E16[G] = (a0 + a1) + (a2 + a3);
        }
    }
    gsync(bar, 2);

    // ======================= Phase 3: hist finalize + W1 GEMV ==============
    if (blk < 256) {
        const int b = blk;
        const int f = b >> 1, bin0 = (b & 1) * 16;

        float4 wr[16];
        #pragma unroll
        for (int k = 0; k < 16; ++k)
            wr[k] = *(const float4*)(W1 + (size_t)(b * 16 + k) * H1 + t * 4);

        float* hl = (float*)smem;
        if (t < 17) {
            const float* p = E16 + (bin0 + t) * FDIM + f;
            float a0 = 0, a1 = 0, a2 = 0, a3 = 0;
            #pragma unroll
            for (int g = 0; g < 16; g += 4) {
                a0 += p[(size_t)(g + 0) * CELLS];
                a1 += p[(size_t)(g + 1) * CELLS];
                a2 += p[(size_t)(g + 2) * CELLS];
                a3 += p[(size_t)(g + 3) * CELLS];
            }
            hl[t] = (a0 + a1) + (a2 + a3);
        }
        __syncthreads();

        float4 acc = {0, 0, 0, 0};
        #pragma unroll
        for (int k = 0; k < 16; ++k) {
            const float h = (hl[k] - hl[k + 1]) * (1.f / (float)N_SAMP);
            acc.x = fmaf(h, wr[k].x, acc.x);
            acc.y = fmaf(h, wr[k].y, acc.y);
            acc.z = fmaf(h, wr[k].z, acc.z);
            acc.w = fmaf(h, wr[k].w, acc.w);
        }
        *(float4*)(h1_part + (size_t)b * H1 + t * 4) = acc;
    }
    gsync(bar, 3);

    // ======================= Phase 4: h1 finalize + W2 GEMV ================
    if (blk < 64) {
        const int b = blk;

        float2 wr2[16];
        #pragma unroll
        for (int k = 0; k < 16; ++k)
            wr2[k] = *(const float2*)(W2 + (size_t)(b * 16 + k) * H2 + t * 2);

        float* hred = (float*)smem;             // 16*16 floats
        float* hv = (float*)(smem + 1024);      // 16 floats
        const int c = t & 15, qg = t >> 4;
        {
            const float* p0 = h1_part + (size_t)(qg * 16) * H1 + b * 16 + c;
            float a0 = 0, a1 = 0, a2 = 0, a3 = 0;
            #pragma unroll
            for (int p = 0; p < 16; p += 4) {
                a0 += p0[(size_t)(p + 0) * H1];
                a1 += p0[(size_t)(p + 1) * H1];
                a2 += p0[(size_t)(p + 2) * H1];
                a3 += p0[(size_t)(p + 3) * H1];
            }
            hred[c * 16 + qg] = (a0 + a1) + (a2 + a3);
        }
        __syncthreads();
        if (t < 16) {
            float sum = 0.f;
            #pragma unroll
            for (int g = 0; g < 16; ++g) sum += hred[t * 16 + g];
            hv[t] = lrelu(sum + b1[b * 16 + t]);
        }
        __syncthreads();

        float2 acc2 = {0.f, 0.f};
        #pragma unroll
        for (int k = 0; k < 16; ++k) {
            acc2.x = fmaf(hv[k], wr2[k].x, acc2.x);
            acc2.y = fmaf(hv[k], wr2[k].y, acc2.y);
        }
        *(float2*)(h2_part + (size_t)b * H2 + t * 2) = acc2;
    }
    gsync(bar, 4);

    // ======================= Phase 5: h2 finalize + W3 + softmax ===========
    if (blk == 0) {
        float s0 = 0, s1 = 0;
        #pragma unroll 8
        for (int p = 0; p < 64; ++p) {
            s0 += h2_part[(size_t)p * H2 + t];
            s1 += h2_part[(size_t)p * H2 + t + 256];
        }
        const float h0 = lrelu(s0 + b2[t]);
        const float h1v = lrelu(s1 + b2[t + 256]);

        float lc[NC];
        #pragma unroll
        for (int cc = 0; cc < NC; ++cc)
            lc[cc] = h0 * W3[t * NC + cc] + h1v * W3[(t + 256) * NC + cc];
        #pragma unroll
        for (int off = 32; off >= 1; off >>= 1) {
            #pragma unroll
            for (int cc = 0; cc < NC; ++cc) lc[cc] += __shfl_down(lc[cc], off, 64);
        }

        float* wsum = (float*)smem;  // [4][NC]
        if ((t & 63) == 0) {
            #pragma unroll
            for (int cc = 0; cc < NC; ++cc) wsum[(t >> 6) * NC + cc] = lc[cc];
        }
        __syncthreads();

        if (t == 0) {
            float logits[NC];
            float mx = -1e30f;
            #pragma unroll
            for (int cc = 0; cc < NC; ++cc) {
                float v = b3[cc];
                for (int ww = 0; ww < 4; ++ww) v += wsum[ww * NC + cc];
                logits[cc] = v;
                mx = fmaxf(mx, v);
            }
            float ssum = 0.f;
            #pragma unroll
            for (int cc = 0; cc < NC; ++cc) { logits[cc] = __expf(logits[cc] - mx); ssum += logits[cc]; }
            const float inv = 1.f / ssum;
            #pragma unroll
            for (int cc = 0; cc < NC; ++cc) out[cc] = logits[cc] * inv;
        }
    }
}

extern "C" void kernel_launch(void* const* d_in, const int* in_sizes, int n_in,
                              void* d_out, int out_size, void* d_ws, size_t ws_size,
                              hipStream_t stream)
{
    const float* x  = (const float*)d_in[0];
    const float* Wf = (const float*)d_in[1];
    const float* bf = (const float*)d_in[2];
    const float* W1 = (const float*)d_in[3];
    const float* b1 = (const float*)d_in[4];
    const float* W2 = (const float*)d_in[5];
    const float* b2 = (const float*)d_in[6];
    const float* W3 = (const float*)d_in[7];
    const float* b3 = (const float*)d_in[8];
    float* out = (float*)d_out;

    float* ws      = (float*)d_ws;
    float* E_part  = ws;                                      // 512*4224 f (8.65 MB)
    float* E16     = E_part + (size_t)NP * CELLS;             // 16*4224 f
    float* h1_part = E16 + (size_t)16 * CELLS;                // 256*1024 f
    float* h2_part = h1_part + (size_t)256 * H1;              // 64*512 f
    unsigned* bar  = (unsigned*)(h2_part + (size_t)64 * H2);  // 8x16 u32 (64B-aligned)

    hipMemsetAsync(bar, 0, 8 * 16 * sizeof(unsigned), stream);
    fused_all<<<GRID, 256, 0, stream>>>(x, Wf, bf, W1, b1, W2, b2, W3, b3,
                                        E_part, E16, h1_part, h2_part, out,
                                        (unsigned*)bar);
}

// Round 2
// 118.883 us; speedup vs baseline: 4.0233x; 4.0233x over previous
//
#include <hip/hip_runtime.h>
#include <math.h>

#define N_SAMP 16384
#define DIN 128
#define FDIM 128
#define BINS 32
#define NEDGE 33
#define CELLS (FDIM * NEDGE)   // 4224
#define H1 1024
#define H2 512
#define NC 10

#define NP 512                 // phase-1 partials (== grid)
#define ROWS 32                // 512*32 = 16384 samples
#define XBS 136                // bf16 x-tile stride (shorts): 272B rows
#define SSS 132                // fp32 s-tile stride (floats): 2-way banks (free)
#define GRID 512               // 2 blocks/CU x 256 CUs -> all co-resident

#define EXP_3_125 22.7598950f  // e^3.125

typedef __attribute__((ext_vector_type(8))) short bf16x8;
typedef __attribute__((ext_vector_type(4))) float f32x4;

__device__ __forceinline__ float sig_from_t(float t) {
    // sigma = 1/(1+t), t = e^{-z}; t->0 => 1, t->inf => 0 (exact saturation)
    return __builtin_amdgcn_rcpf(1.f + t);
}
__device__ __forceinline__ float lrelu(float x) { return x > 0.f ? x : 0.01f * x; }
__device__ __forceinline__ unsigned short f2bf(float f) {   // RNE fp32->bf16
    unsigned int u = __float_as_uint(f);
    u += 0x7FFF + ((u >> 16) & 1);
    return (unsigned short)(u >> 16);
}

// Cross-phase data exchange: relaxed agent-scope atomics. These compile to
// global_load/store with the coherence bits set (read/write through to the
// Infinity Cache) -- NO buffer_inv / buffer_wbl2 cache maintenance, which is
// what destroyed round 1 (415us of L2-invalidate storms from acquire polls).
__device__ __forceinline__ float ld_cs(const float* p) {
    return __hip_atomic_load(p, __ATOMIC_RELAXED, __HIP_MEMORY_SCOPE_AGENT);
}
__device__ __forceinline__ void st_cs(float* p, float v) {
    __hip_atomic_store(p, v, __ATOMIC_RELAXED, __HIP_MEMORY_SCOPE_AGENT);
}

__device__ __forceinline__ void sig_chain4(float za, float zb, float zc, float zd,
                                           float* locE) {
    // four interleaved telescoped chains (row quad) for 4x trans-unit ILP
    float ta = __expf(za), tb = __expf(zb), tc = __expf(zc), td = __expf(zd);
    #pragma unroll
    for (int j = 0; j < 12; ++j) {
        locE[j] += (sig_from_t(ta) + sig_from_t(tb)) +
                   (sig_from_t(tc) + sig_from_t(td));
        ta *= EXP_3_125; tb *= EXP_3_125; tc *= EXP_3_125; td *= EXP_3_125;
    }
}

// ---------------------------------------------------------------------------
// Barrier: pure relaxed atomics, zero fences. Data visibility is carried by
// the sc-bit data ops themselves; ordering (data before flag) is carried by
// the vmcnt(0) drain that __syncthreads performs before s_barrier, plus an
// explicit belt-and-braces waitcnt. 8 x 128B-padded counters, monotonic,
// zeroed by a 1KB memset each launch. Failsafe timeout (~20ms) fails fast
// instead of hanging if co-residency is ever violated.
// ---------------------------------------------------------------------------
__device__ __forceinline__ void arrive(unsigned* bar) {
    __syncthreads();                                  // drains vmcnt for all threads
    if (threadIdx.x == 0) {
        asm volatile("s_waitcnt vmcnt(0)" ::: "memory");
        __hip_atomic_fetch_add(&bar[(blockIdx.x & 7) * 32], 1u,
                               __ATOMIC_RELAXED, __HIP_MEMORY_SCOPE_AGENT);
    }
}
__device__ __forceinline__ void wait_for(unsigned* bar, unsigned tgt) {
    if (threadIdx.x == 0) {
        const unsigned long long t0 = __builtin_amdgcn_s_memrealtime();
        for (;;) {
            unsigned mn = 0xffffffffu;
            #pragma unroll
            for (int i = 0; i < 8; ++i)
                mn = min(mn, __hip_atomic_load(&bar[i * 32], __ATOMIC_RELAXED,
                                               __HIP_MEMORY_SCOPE_AGENT));
            if (mn >= tgt) break;
            if (__builtin_amdgcn_s_memrealtime() - t0 > 2000000ull) break;
            __builtin_amdgcn_s_sleep(16);
        }
    }
    __syncthreads();   // full compiler+block barrier; phase reads stay below
}

// ---------------------------------------------------------------------------
// Fused persistent kernel: 512 blocks x 256 threads, 5 phases, 4 barriers.
// Participant sets are nested (512 -> 264 -> 256 -> 64 -> 1); blocks retire
// as soon as their last phase is done, so barrier arrival counts shrink:
// cumulative per-residue targets 64 / 97 / 129 / 137 (all exactly /8).
// Phase bodies are bit-identical to the verified 5-kernel version.
// ---------------------------------------------------------------------------
__global__ __launch_bounds__(256, 2) void fused_all(
    const float* __restrict__ x, const float* __restrict__ Wf,
    const float* __restrict__ bfeat,
    const float* __restrict__ W1, const float* __restrict__ b1,
    const float* __restrict__ W2, const float* __restrict__ b2,
    const float* __restrict__ W3, const float* __restrict__ b3,
    float* __restrict__ E_part, float* __restrict__ E16,
    float* __restrict__ h1_part, float* __restrict__ h2_part,
    float* __restrict__ out, unsigned* __restrict__ bar)
{
    __shared__ __align__(16) char smem[ROWS * XBS * 2 + ROWS * SSS * 4]; // 25600 B
    const int t = threadIdx.x;
    const int blk = blockIdx.x;

    // ======================= Phase 1: feats GEMM + sigmoid + hist ==========
    {
        unsigned short* xbf = (unsigned short*)smem;            // 8704 B
        float* s = (float*)(smem + ROWS * XBS * 2);             // 16896 B
        const int w = t >> 6, L = t & 63;
        const int m = L & 15, q = L >> 4;

        // B fragments straight from L2-hot Wf (transposed access)
        bf16x8 bfrag[2][4];
        #pragma unroll
        for (int fh = 0; fh < 2; ++fh) {
            const int n = w * 32 + fh * 16 + m;
            #pragma unroll
            for (int kc = 0; kc < 4; ++kc) {
                const float* wp = Wf + (size_t)(kc * 32 + q * 8) * FDIM + n;
                bf16x8 bfv;
                #pragma unroll
                for (int j = 0; j < 8; ++j)
                    bfv[j] = (short)f2bf(wp[j * FDIM]);
                bfrag[fh][kc] = bfv;
            }
        }

        // stage x tile as bf16: 32 rows x 128 cols
        const int row0 = blk * ROWS;
        #pragma unroll
        for (int i = 0; i < 4; ++i) {
            const int idx = t + i * 256;
            const int r = idx >> 5, c4 = (idx & 31) << 2;
            const float4 v = *(const float4*)(x + (size_t)(row0 + r) * DIN + c4);
            unsigned short* p = &xbf[r * XBS + c4];
            p[0] = f2bf(v.x); p[1] = f2bf(v.y); p[2] = f2bf(v.z); p[3] = f2bf(v.w);
        }
        __syncthreads();

        f32x4 acc[2][2];
        #pragma unroll
        for (int rt = 0; rt < 2; ++rt)
            #pragma unroll
            for (int fh = 0; fh < 2; ++fh)
                acc[rt][fh] = (f32x4){0.f, 0.f, 0.f, 0.f};

        #pragma unroll
        for (int kc = 0; kc < 4; ++kc) {
            const bf16x8 a0 = *(const bf16x8*)&xbf[m * XBS + kc * 32 + q * 8];
            const bf16x8 a1 = *(const bf16x8*)&xbf[(16 + m) * XBS + kc * 32 + q * 8];
            acc[0][0] = __builtin_amdgcn_mfma_f32_16x16x32_bf16(a0, bfrag[0][kc], acc[0][0], 0, 0, 0);
            acc[0][1] = __builtin_amdgcn_mfma_f32_16x16x32_bf16(a0, bfrag[1][kc], acc[0][1], 0, 0, 0);
            acc[1][0] = __builtin_amdgcn_mfma_f32_16x16x32_bf16(a1, bfrag[0][kc], acc[1][0], 0, 0, 0);
            acc[1][1] = __builtin_amdgcn_mfma_f32_16x16x32_bf16(a1, bfrag[1][kc], acc[1][1], 0, 0, 0);
        }

        // sigmoid epilogue in C-layout: col = m (feat), row = q*4 + reg
        {
            const int f0 = w * 32 + m;
            const float bb0 = bfeat[f0], bb1 = bfeat[f0 + 16];
            #pragma unroll
            for (int rt = 0; rt < 2; ++rt)
                #pragma unroll
                for (int r = 0; r < 4; ++r) {
                    const int row = rt * 16 + q * 4 + r;
                    s[row * SSS + f0]      = sig_from_t(__expf(-(acc[rt][0][r] + bb0)));
                    s[row * SSS + f0 + 16] = sig_from_t(__expf(-(acc[rt][1][r] + bb1)));
                }
        }
        __syncthreads();

        // trimmed edge sums: thread = (feat, half); 12 chained edges each
        const int feat = t & 127;
        const int eg = t >> 7;                       // wave-uniform
        const float c0 = eg ? 50.0f : 12.5f;

        float locE[12];
        #pragma unroll
        for (int j = 0; j < 12; ++j) locE[j] = 0.f;

        for (int r = 0; r < ROWS; r += 4) {
            const float za = c0 - 100.f * s[r * SSS + feat];
            const float zb = c0 - 100.f * s[(r + 1) * SSS + feat];
            const float zc = c0 - 100.f * s[(r + 2) * SSS + feat];
            const float zd = c0 - 100.f * s[(r + 3) * SSS + feat];
            sig_chain4(za, zb, zc, zd, locE);
        }

        // write-through partial stores (consumed cross-XCD in phase 2)
        float* dst = E_part + (size_t)blk * CELLS + feat;
        if (eg == 0) {
            #pragma unroll
            for (int j = 0; j < 4; ++j)  st_cs(&dst[j * FDIM], (float)ROWS);
            #pragma unroll
            for (int j = 0; j < 12; ++j) st_cs(&dst[(4 + j) * FDIM], locE[j]);
        } else {
            #pragma unroll
            for (int j = 0; j < 12; ++j) st_cs(&dst[(16 + j) * FDIM], locE[j]);
            #pragma unroll
            for (int j = 28; j < 33; ++j) st_cs(&dst[j * FDIM], 0.f);
        }
    }
    arrive(bar);                       // barrier 1: 512 arrivals (cum 64/ctr)
    if (blk >= 264) return;
    wait_for(bar, 64);

    // ======================= Phase 2: reduce 512 -> 16 partials ============
    {
        const unsigned G = (unsigned)blk * 256u + (unsigned)t;   // < 16*CELLS
        const unsigned pg = G / CELLS, cell = G % CELLS;
        const float* p = E_part + (size_t)pg * 32 * CELLS + cell;
        float a0 = 0, a1 = 0, a2 = 0, a3 = 0;
        #pragma unroll
        for (int qq = 0; qq < 32; qq += 4) {
            a0 += ld_cs(&p[(size_t)(qq + 0) * CELLS]);
            a1 += ld_cs(&p[(size_t)(qq + 1) * CELLS]);
            a2 += ld_cs(&p[(size_t)(qq + 2) * CELLS]);
            a3 += ld_cs(&p[(size_t)(qq + 3) * CELLS]);
        }
        st_cs(&E16[G], (a0 + a1) + (a2 + a3));
    }
    arrive(bar);                       // barrier 2: 264 arrivals (cum 97/ctr)
    if (blk >= 256) return;
    wait_for(bar, 97);

    // ======================= Phase 3: hist finalize + W1 GEMV ==============
    {
        const int b = blk;
        const int f = b >> 1, bin0 = (b & 1) * 16;

        float4 wr[16];
        #pragma unroll
        for (int k = 0; k < 16; ++k)
            wr[k] = *(const float4*)(W1 + (size_t)(b * 16 + k) * H1 + t * 4);

        float* hl = (float*)smem;
        if (t < 17) {
            const float* p = E16 + (bin0 + t) * FDIM + f;
            float a0 = 0, a1 = 0, a2 = 0, a3 = 0;
            #pragma unroll
            for (int g = 0; g < 16; g += 4) {
                a0 += ld_cs(&p[(size_t)(g + 0) * CELLS]);
                a1 += ld_cs(&p[(size_t)(g + 1) * CELLS]);
                a2 += ld_cs(&p[(size_t)(g + 2) * CELLS]);
                a3 += ld_cs(&p[(size_t)(g + 3) * CELLS]);
            }
            hl[t] = (a0 + a1) + (a2 + a3);
        }
        __syncthreads();

        float4 acc = {0, 0, 0, 0};
        #pragma unroll
        for (int k = 0; k < 16; ++k) {
            const float h = (hl[k] - hl[k + 1]) * (1.f / (float)N_SAMP);
            acc.x = fmaf(h, wr[k].x, acc.x);
            acc.y = fmaf(h, wr[k].y, acc.y);
            acc.z = fmaf(h, wr[k].z, acc.z);
            acc.w = fmaf(h, wr[k].w, acc.w);
        }
        float* hp = h1_part + (size_t)b * H1 + t * 4;
        st_cs(&hp[0], acc.x); st_cs(&hp[1], acc.y);
        st_cs(&hp[2], acc.z); st_cs(&hp[3], acc.w);
    }
    arrive(bar);                       // barrier 3: 256 arrivals (cum 129/ctr)
    if (blk >= 64) return;
    wait_for(bar, 129);

    // ======================= Phase 4: h1 finalize + W2 GEMV ================
    {
        const int b = blk;

        float2 wr2[16];
        #pragma unroll
        for (int k = 0; k < 16; ++k)
            wr2[k] = *(const float2*)(W2 + (size_t)(b * 16 + k) * H2 + t * 2);

        float* hred = (float*)smem;             // 16*16 floats
        float* hv = (float*)(smem + 1024);      // 16 floats
        const int c = t & 15, qg = t >> 4;
        {
            const float* p0 = h1_part + (size_t)(qg * 16) * H1 + b * 16 + c;
            float a0 = 0, a1 = 0, a2 = 0, a3 = 0;
            #pragma unroll
            for (int p = 0; p < 16; p += 4) {
                a0 += ld_cs(&p0[(size_t)(p + 0) * H1]);
                a1 += ld_cs(&p0[(size_t)(p + 1) * H1]);
                a2 += ld_cs(&p0[(size_t)(p + 2) * H1]);
                a3 += ld_cs(&p0[(size_t)(p + 3) * H1]);
            }
            hred[c * 16 + qg] = (a0 + a1) + (a2 + a3);
        }
        __syncthreads();
        if (t < 16) {
            float sum = 0.f;
            #pragma unroll
            for (int g = 0; g < 16; ++g) sum += hred[t * 16 + g];
            hv[t] = lrelu(sum + b1[b * 16 + t]);
        }
        __syncthreads();

        float2 acc2 = {0.f, 0.f};
        #pragma unroll
        for (int k = 0; k < 16; ++k) {
            acc2.x = fmaf(hv[k], wr2[k].x, acc2.x);
            acc2.y = fmaf(hv[k], wr2[k].y, acc2.y);
        }
        float* hp2 = h2_part + (size_t)b * H2 + t * 2;
        st_cs(&hp2[0], acc2.x); st_cs(&hp2[1], acc2.y);
    }
    arrive(bar);                       // barrier 4: 64 arrivals (cum 137/ctr)
    if (blk >= 1) return;
    wait_for(bar, 137);

    // ======================= Phase 5: h2 finalize + W3 + softmax ===========
    {
        float s0 = 0, s1 = 0;
        #pragma unroll 8
        for (int p = 0; p < 64; ++p) {
            s0 += ld_cs(&h2_part[(size_t)p * H2 + t]);
            s1 += ld_cs(&h2_part[(size_t)p * H2 + t + 256]);
        }
        const float h0 = lrelu(s0 + b2[t]);
        const float h1v = lrelu(s1 + b2[t + 256]);

        float lc[NC];
        #pragma unroll
        for (int cc = 0; cc < NC; ++cc)
            lc[cc] = h0 * W3[t * NC + cc] + h1v * W3[(t + 256) * NC + cc];
        #pragma unroll
        for (int off = 32; off >= 1; off >>= 1) {
            #pragma unroll
            for (int cc = 0; cc < NC; ++cc) lc[cc] += __shfl_down(lc[cc], off, 64);
        }

        float* wsum = (float*)smem;  // [4][NC]
        if ((t & 63) == 0) {
            #pragma unroll
            for (int cc = 0; cc < NC; ++cc) wsum[(t >> 6) * NC + cc] = lc[cc];
        }
        __syncthreads();

        if (t == 0) {
            float logits[NC];
            float mx = -1e30f;
            #pragma unroll
            for (int cc = 0; cc < NC; ++cc) {
                float v = b3[cc];
                for (int ww = 0; ww < 4; ++ww) v += wsum[ww * NC + cc];
                logits[cc] = v;
                mx = fmaxf(mx, v);
            }
            float ssum = 0.f;
            #pragma unroll
            for (int cc = 0; cc < NC; ++cc) { logits[cc] = __expf(logits[cc] - mx); ssum += logits[cc]; }
            const float inv = 1.f / ssum;
            #pragma unroll
            for (int cc = 0; cc < NC; ++cc) out[cc] = logits[cc] * inv;
        }
    }
}

extern "C" void kernel_launch(void* const* d_in, const int* in_sizes, int n_in,
                              void* d_out, int out_size, void* d_ws, size_t ws_size,
                              hipStream_t stream)
{
    const float* x  = (const float*)d_in[0];
    const float* Wf = (const float*)d_in[1];
    const float* bf = (const float*)d_in[2];
    const float* W1 = (const float*)d_in[3];
    const float* b1 = (const float*)d_in[4];
    const float* W2 = (const float*)d_in[5];
    const float* b2 = (const float*)d_in[6];
    const float* W3 = (const float*)d_in[7];
    const float* b3 = (const float*)d_in[8];
    float* out = (float*)d_out;

    float* ws      = (float*)d_ws;
    float* E_part  = ws;                                      // 512*4224 f (8.65 MB)
    float* E16     = E_part + (size_t)NP * CELLS;             // 16*4224 f
    float* h1_part = E16 + (size_t)16 * CELLS;                // 256*1024 f
    float* h2_part = h1_part + (size_t)256 * H1;              // 64*512 f
    unsigned* bar  = (unsigned*)(h2_part + (size_t)64 * H2);  // 8 x 128B-padded u32

    hipMemsetAsync(bar, 0, 8 * 32 * sizeof(unsigned), stream);
    fused_all<<<GRID, 256, 0, stream>>>(x, Wf, bf, W1, b1, W2, b2, W3, b3,
                                        E_part, E16, h1_part, h2_part, out,
                                        (unsigned*)bar);
}